// Round 11
// baseline (1367.014 us; speedup 1.0000x reference)
//
#include <hip/hip_runtime.h>
#include <hip/hip_bf16.h>
#include <cstdint>

typedef __attribute__((ext_vector_type(8))) short short8;
typedef __attribute__((ext_vector_type(4))) float f32x4;

#define NS 512
#define NB 32
#define NE 768
#define NH 128
#define NT 15
#define NM (NB*NS)      // 16384 rows, m = b*512 + s
#define LP 136          // hfrag row pitch (bf16): 272B, 16B-aligned rows

__device__ __forceinline__ float bflo(unsigned int u){ return __builtin_bit_cast(float, u << 16); }
__device__ __forceinline__ float bfhi(unsigned int u){ return __builtin_bit_cast(float, u & 0xffff0000u); }
__device__ __forceinline__ float sigf(float x){ return __fdividef(1.f, 1.f + __expf(-x)); }
__device__ __forceinline__ float tanhf_(float x){ return 1.f - __fdividef(2.f, __expf(2.f*x) + 1.f); }

// raw workgroup barrier: LDS-drain only, global loads/stores stay in flight.
__device__ __forceinline__ void lds_barrier() {
  asm volatile("s_waitcnt lgkmcnt(0)" ::: "memory");
  __builtin_amdgcn_s_barrier();
  asm volatile("" ::: "memory");
}

__device__ __forceinline__ void gload16(const void* g, void* l) {
#if __has_builtin(__builtin_amdgcn_global_load_lds)
  __builtin_amdgcn_global_load_lds((const __attribute__((address_space(1))) void*)g,
                                   (__attribute__((address_space(3))) void*)l, 16, 0, 0);
#else
  *(uint4*)l = *(const uint4*)g;
#endif
}

// ---------------- converts ----------------
__global__ void cvt_bf16_kernel(const float* __restrict__ in,
                                __hip_bfloat16* __restrict__ out, int n4) {
  int i = blockIdx.x*blockDim.x + threadIdx.x;
  int stride = gridDim.x*blockDim.x;
  for (int j = i; j < n4; j += stride) {
    float4 v = ((const float4*)in)[j];
    ushort4 o;
    o.x = __builtin_bit_cast(unsigned short, __float2bfloat16(v.x));
    o.y = __builtin_bit_cast(unsigned short, __float2bfloat16(v.y));
    o.z = __builtin_bit_cast(unsigned short, __float2bfloat16(v.z));
    o.w = __builtin_bit_cast(unsigned short, __float2bfloat16(v.w));
    ((ushort4*)out)[j] = o;
  }
}

__global__ void bias_kernel(const float* __restrict__ bihf, const float* __restrict__ bhhf,
                            const float* __restrict__ bihb, const float* __restrict__ bhhb,
                            float* __restrict__ bias) {
  int i = blockIdx.x*blockDim.x + threadIdx.x;
  if (i < 512)       bias[i] = bihf[i] + bhhf[i];
  else if (i < 1024) bias[i] = bihb[i-512] + bhhb[i-512];
}

// ---------------- xproj GEMM: A[16384x768] @ Bw[1024x768]^T -> xprep (lane-ordered) ----------------
// Bw rows natural: col = dir*512 + n, n = g*128 + j.
// xprep[dir][bg][s][w][l][e=r*4+jjb] bf16: lane (w,l) of lstm block (dir,bg) reads
// its 16 per-step x values as ONE contiguous 32B load.
__global__ __launch_bounds__(256, 2) void gemm_xproj(
    const __hip_bfloat16* __restrict__ A,
    const __hip_bfloat16* __restrict__ Bw,
    const float* __restrict__ biasp,
    __hip_bfloat16* __restrict__ xprep)
{
  __shared__ __align__(16) __hip_bfloat16 As[128*64];
  __shared__ __align__(16) __hip_bfloat16 Bs[128*64];
  const int bm = blockIdx.x * 128;
  const int bn = blockIdx.y * 128;
  const int tid = threadIdx.x;
  const int lane = tid & 63;
  const int wv = tid >> 6;
  const int wr = wv >> 1, wc = wv & 1;
  char* AsB = (char*)As;
  char* BsB = (char*)Bs;
  const char* Ab = (const char*)A;
  const char* Bb = (const char*)Bw;
  f32x4 acc[4][4] = {};

  for (int kt = 0; kt < 12; ++kt) {
    const int k0 = kt * 64;
    __syncthreads();
    #pragma unroll
    for (int i = 0; i < 4; ++i) {
      int fb = i*4096 + tid*16;
      int r  = fb >> 7;
      int cb = fb & 127;
      gload16(Ab + ((size_t)(bm + r)*768 + k0)*2 + cb, AsB + fb);
      gload16(Bb + ((size_t)(bn + r)*768 + k0)*2 + cb, BsB + fb);
    }
    __syncthreads();
    #pragma unroll
    for (int ks = 0; ks < 2; ++ks) {
      const int krow = ks*32 + ((lane >> 4) << 3);
      short8 af[4], bfr[4];
      #pragma unroll
      for (int m = 0; m < 4; ++m) {
        int row = wr*64 + m*16 + (lane & 15);
        af[m] = *(const short8*)(AsB + (row*64 + krow)*2);
      }
      #pragma unroll
      for (int n = 0; n < 4; ++n) {
        int row = wc*64 + n*16 + (lane & 15);
        bfr[n] = *(const short8*)(BsB + (row*64 + krow)*2);
      }
      #pragma unroll
      for (int m = 0; m < 4; ++m)
        #pragma unroll
        for (int n = 0; n < 4; ++n)
          acc[m][n] = __builtin_amdgcn_mfma_f32_16x16x32_bf16(af[m], bfr[n], acc[m][n], 0, 0, 0);
    }
  }
  #pragma unroll
  for (int m = 0; m < 4; ++m) {
    #pragma unroll
    for (int n = 0; n < 4; ++n) {
      const int col = bn + wc*64 + n*16 + (lane & 15);
      const float bv = biasp[col];
      const int dir = col >> 9;
      const int nn  = col & 511;
      const int r = nn >> 7, jpos = nn & 127;
      const int w2 = jpos >> 4, l15 = jpos & 15;
      #pragma unroll
      for (int jj = 0; jj < 4; ++jj) {
        const int row = bm + wr*64 + m*16 + ((lane >> 4)*4 + jj);
        const int b = row >> 9, s = row & 511;
        const int bg = b >> 4, bl = b & 15;
        const size_t idx = (((((size_t)(dir*2 + bg)*512 + s)*8 + w2)*64
                            + ((bl >> 2)*16 + l15))*16 + (r*4 + (bl & 3)));
        xprep[idx] = __float2bfloat16(acc[m][n][jj] + bv);
      }
    }
  }
}

// ---------------- LSTM: swapped-operand MFMA, in-lane activation, 1 barrier/step ----------------
// 4 blocks = (dir 0..1) x (bg 0..1), 16 real batches each, 512 threads = 8 waves.
// z = h[16 x 128] @ Whh^T: A = h (M=batches), B = Whh rows (N = n = g*128+j).
// Wave w, tile r=gate: cols n = r*128 + w*16 + (lane&15). Lane holds, in acc[r][jj],
// gate r of j = w*16+(lane&15) for batch (lane>>4)*4+jj -> activation fully in-lane.
// h -> LDS [batch][j] (pitch LP, dbuf) with 4 ds_write_b16; next step's A-frag reads it.
__global__ __launch_bounds__(512) __attribute__((amdgpu_waves_per_eu(1, 2)))
void lstm_mfma(
    const __hip_bfloat16* __restrict__ xprep,  // [2][2][512][8][64][16]
    const __hip_bfloat16* __restrict__ whhbf,  // [2][512][128] natural rows
    float* __restrict__ hf,                    // [NM][128]
    float* __restrict__ hb)                    // [NM][128]
{
  __shared__ __align__(16) __hip_bfloat16 hfrag[2][16*LP];

  const int bid = blockIdx.x;          // 0..3
  const int dir = bid >> 1, bg = bid & 1;
  const int t = threadIdx.x;
  const int w = t >> 6, l = t & 63;
  const int ln = l & 15, lp = l >> 4;

  // B-frags (weights): tile r covers n = r*128 + w*16 + ln; k = lp*8 + kc*32 + [0,8)
  uint4 bfw[4][4];
  {
    const char* wb = (const char*)(whhbf + (size_t)dir*512*128);
    #pragma unroll
    for (int r = 0; r < 4; ++r) {
      const int n = r*128 + w*16 + ln;
      #pragma unroll
      for (int kc = 0; kc < 4; ++kc)
        bfw[r][kc] = *(const uint4*)(wb + ((size_t)n*128 + lp*8 + kc*32)*2);
    }
  }

  for (int i = t; i < 2*16*LP; i += 512) ((unsigned short*)hfrag)[i] = 0;

  const __hip_bfloat16* xb = xprep +
      ((((size_t)(dir*2 + bg)*512)*8 + w)*64 + l)*16;   // + s*8192

  const int jl = w*16 + ln;
  float* houtb = (dir ? hb : hf) + ((size_t)(bg*16 + lp*4)*512)*128 + jl;

  float cc[4] = {0.f, 0.f, 0.f, 0.f};

  uint4 xs0[2], xs1[2], xs2[2], xs3[2];
  {
    const int s0 = dir ? 511 : 0, s1 = dir ? 510 : 1, s2 = dir ? 509 : 2, s3 = dir ? 508 : 3;
    const uint4* p0 = (const uint4*)(xb + (size_t)s0*8192);
    const uint4* p1 = (const uint4*)(xb + (size_t)s1*8192);
    const uint4* p2 = (const uint4*)(xb + (size_t)s2*8192);
    const uint4* p3 = (const uint4*)(xb + (size_t)s3*8192);
    xs0[0]=p0[0]; xs0[1]=p0[1]; xs1[0]=p1[0]; xs1[1]=p1[1];
    xs2[0]=p2[0]; xs2[1]=p2[1]; xs3[0]=p3[0]; xs3[1]=p3[1];
  }
  __syncthreads();   // prologue only

  auto STEP = [&](int si, int bufc, uint4 (&xs)[2]) {
    const int s = dir ? (511 - si) : si;

    // prefetch x for si+4 (4-step latency cover; stays in flight across barrier)
    uint4 t0 = xs[0], t1 = xs[1];
    const int fi = si + 4;
    if (fi < 512) {
      const int fl = dir ? (511 - fi) : fi;
      const uint4* p = (const uint4*)(xb + (size_t)fl*8192);
      t0 = p[0]; t1 = p[1];
    }

    // A-frags: h from LDS, lane&15 = batch row, k-slice lp*8 + kc*32
    short8 af[4];
    #pragma unroll
    for (int kc = 0; kc < 4; ++kc)
      af[kc] = *(const short8*)((const char*)hfrag + bufc*(16*LP*2)
                                + (ln*LP + lp*8 + kc*32)*2);

    f32x4 acc[4];
    #pragma unroll
    for (int r = 0; r < 4; ++r) {
      acc[r] = f32x4{0.f, 0.f, 0.f, 0.f};
      #pragma unroll
      for (int kc = 0; kc < 4; ++kc)
        acc[r] = __builtin_amdgcn_mfma_f32_16x16x32_bf16(
                   af[kc], __builtin_bit_cast(short8, bfw[r][kc]), acc[r], 0, 0, 0);
    }

    // x unpack: e = r*4 + jj -> dword e>>1, half e&1
    const unsigned xv[8] = {xs[0].x, xs[0].y, xs[0].z, xs[0].w,
                            xs[1].x, xs[1].y, xs[1].z, xs[1].w};

    // in-lane activation: 4 batches (jj), all 64 lanes busy
    #pragma unroll
    for (int jj = 0; jj < 4; ++jj) {
      const float xi = ((0*4+jj)&1) ? bfhi(xv[(0*4+jj)>>1]) : bflo(xv[(0*4+jj)>>1]);
      const float xf = ((1*4+jj)&1) ? bfhi(xv[(1*4+jj)>>1]) : bflo(xv[(1*4+jj)>>1]);
      const float xg = ((2*4+jj)&1) ? bfhi(xv[(2*4+jj)>>1]) : bflo(xv[(2*4+jj)>>1]);
      const float xo = ((3*4+jj)&1) ? bfhi(xv[(3*4+jj)>>1]) : bflo(xv[(3*4+jj)>>1]);
      const float zi = acc[0][jj] + xi;
      const float zf = acc[1][jj] + xf;
      const float zg = acc[2][jj] + xg;
      const float zo = acc[3][jj] + xo;
      cc[jj] = sigf(zf)*cc[jj] + sigf(zi)*tanhf_(zg);
      const float h = sigf(zo)*tanhf_(cc[jj]);
      hfrag[bufc ^ 1][(lp*4 + jj)*LP + jl] = __float2bfloat16(h);
      houtb[(size_t)jj*512*128 + (size_t)s*128] = h;   // fire-and-forget
    }
    xs[0] = t0; xs[1] = t1;
    lds_barrier();
  };

  for (int p4 = 0; p4 < 128; ++p4) {
    // pin weights to AGPRs (R9-proven residency mechanism)
    #pragma unroll
    for (int r = 0; r < 4; ++r)
      #pragma unroll
      for (int kc = 0; kc < 4; ++kc)
        asm volatile("" : "+a"(bfw[r][kc].x), "+a"(bfw[r][kc].y),
                          "+a"(bfw[r][kc].z), "+a"(bfw[r][kc].w));
    const int base = p4*4;
    STEP(base + 0, 0, xs0);
    STEP(base + 1, 1, xs1);
    STEP(base + 2, 0, xs2);
    STEP(base + 3, 1, xs3);
  }
}

// ---------------- emissions: em[m][t] = [hf|hb][m] . Wp[t] + bp[t] ----------------
__global__ __launch_bounds__(256) void em_kernel(
    const float* __restrict__ hf, const float* __restrict__ hb,
    const float* __restrict__ Wp, const float* __restrict__ bp,
    float* __restrict__ em)
{
  __shared__ float wps[15*256];
  __shared__ float bps[15];
  const int tid = threadIdx.x;
  for (int i = tid; i < 15*256; i += 256) wps[i] = Wp[i];
  if (tid < 15) bps[tid] = bp[tid];
  __syncthreads();
  const size_t m = (size_t)blockIdx.x*256 + tid;
  float acc[15];
  #pragma unroll
  for (int t2 = 0; t2 < 15; ++t2) acc[t2] = bps[t2];
  const float4* hf4 = (const float4*)(hf + m*128);
  const float4* hb4 = (const float4*)(hb + m*128);
  for (int kc = 0; kc < 32; ++kc) {
    float4 hv = hf4[kc];
    #pragma unroll
    for (int t2 = 0; t2 < 15; ++t2)
      acc[t2] += hv.x*wps[t2*256 + kc*4+0] + hv.y*wps[t2*256 + kc*4+1]
               + hv.z*wps[t2*256 + kc*4+2] + hv.w*wps[t2*256 + kc*4+3];
  }
  for (int kc = 0; kc < 32; ++kc) {
    float4 hv = hb4[kc];
    #pragma unroll
    for (int t2 = 0; t2 < 15; ++t2)
      acc[t2] += hv.x*wps[t2*256 + 128 + kc*4+0] + hv.y*wps[t2*256 + 128 + kc*4+1]
               + hv.z*wps[t2*256 + 128 + kc*4+2] + hv.w*wps[t2*256 + 128 + kc*4+3];
  }
  float* eo = em + m*15;
  #pragma unroll
  for (int t2 = 0; t2 < 15; ++t2) eo[t2] = acc[t2];
}

// ---------------- CRF NLL: one block (1 wave) per batch -> partial per b ----------------
__global__ __launch_bounds__(64) void crf_kernel(
    const float* __restrict__ em,
    const int* __restrict__ tags, const int* __restrict__ mask,
    const float* __restrict__ trans, const float* __restrict__ start_t,
    const float* __restrict__ end_t, float* __restrict__ nllb)
{
  __shared__ __align__(16) float ems[512*15];
  __shared__ float trs[225];
  __shared__ int tgs[512];
  __shared__ int mks[512];
  const int b = blockIdx.x, j = threadIdx.x;
  const float* emb = em + (size_t)b*512*15;
  {
    const float4* s4 = (const float4*)emb;
    float4* d4 = (float4*)ems;
    for (int i = j; i < 512*15/4; i += 64) d4[i] = s4[i];
    for (int i = j; i < 512; i += 64) { tgs[i] = tags[b*512+i]; mks[i] = mask[b*512+i]; }
    for (int i = j; i < 225; i += 64) trs[i] = trans[i];
  }
  __syncthreads();

  float trc[15];
  #pragma unroll
  for (int i = 0; i < 15; ++i) trc[i] = (j < 15) ? trs[i*15 + j] : 0.f;

  float alpha = (j < 15) ? (start_t[j] + ems[j]) : -3.0e38f;
  for (int s = 1; s < 512; ++s) {
    const float emv = (j < 15) ? ems[s*15 + j] : 0.f;
    const int msk = mks[s];
    float v[15];
    #pragma unroll
    for (int i = 0; i < 15; ++i) {
      const float ai = __shfl(alpha, i, 64);
      v[i] = ai + trc[i];
    }
    const float t01 = fmaxf(v[0], v[1]),  t23 = fmaxf(v[2], v[3]);
    const float t45 = fmaxf(v[4], v[5]),  t67 = fmaxf(v[6], v[7]);
    const float t89 = fmaxf(v[8], v[9]),  tab = fmaxf(v[10], v[11]);
    const float tcd = fmaxf(v[12], v[13]);
    const float q0 = fmaxf(t01, t23), q1 = fmaxf(t45, t67);
    const float q2 = fmaxf(t89, tab), q3 = fmaxf(tcd, v[14]);
    const float mx = fmaxf(fmaxf(q0, q1), fmaxf(q2, q3));
    float e[15];
    #pragma unroll
    for (int i = 0; i < 15; ++i) e[i] = __expf(v[i] - mx);
    const float s01 = e[0]+e[1], s23 = e[2]+e[3], s45 = e[4]+e[5], s67 = e[6]+e[7];
    const float s89 = e[8]+e[9], sab = e[10]+e[11], scd = e[12]+e[13];
    const float u0 = s01+s23, u1 = s45+s67, u2 = s89+sab, u3 = scd+e[14];
    const float sum = (u0+u1) + (u2+u3);
    const float nxt = emv + mx + __logf(sum);
    if (msk > 0 && j < 15) alpha = nxt;
  }
  float vz = (j < 15) ? (alpha + end_t[j]) : -3.0e38f;
  float mz = vz;
  #pragma unroll
  for (int off = 32; off > 0; off >>= 1) mz = fmaxf(mz, __shfl_xor(mz, off, 64));
  float se = (j < 15) ? __expf(vz - mz) : 0.f;
  #pragma unroll
  for (int off = 32; off > 0; off >>= 1) se += __shfl_xor(se, off, 64);
  const float logZ = mz + __logf(se);

  float sc = 0.f; int cnt = 0;
  for (int s = j; s < 512; s += 64) cnt += (mks[s] ? 1 : 0);
  for (int s = 1 + j; s < 512; s += 64) {
    if (mks[s]) {
      const int tp = tgs[s-1], tc = tgs[s];
      sc += trs[tp*15 + tc] + ems[s*15 + tc];
    }
  }
  #pragma unroll
  for (int off = 32; off > 0; off >>= 1) {
    sc  += __shfl_xor(sc, off, 64);
    cnt += __shfl_xor(cnt, off, 64);
  }
  if (j == 0) {
    const int t0 = tgs[0];
    sc += start_t[t0] + ems[t0];
    int last = cnt - 1; if (last < 0) last = 0;
    sc += end_t[tgs[last]];
    nllb[b] = logZ - sc;
  }
}

__global__ __launch_bounds__(64) void nll_reduce_kernel(const float* __restrict__ nllb,
                                                        float* __restrict__ out) {
  const int j = threadIdx.x;
  float v = (j < 32) ? nllb[j] : 0.f;
  #pragma unroll
  for (int off = 32; off > 0; off >>= 1) v += __shfl_xor(v, off, 64);
  if (j == 0) out[0] = v;
}

// ---------------- launch ----------------
extern "C" void kernel_launch(void* const* d_in, const int* in_sizes, int n_in,
                              void* d_out, int out_size, void* d_ws, size_t ws_size,
                              hipStream_t stream) {
  const float* x      = (const float*)d_in[0];
  const int*   tags   = (const int*)d_in[1];
  const int*   mask   = (const int*)d_in[2];
  const float* Wih_f  = (const float*)d_in[3];
  const float* Whh_f  = (const float*)d_in[4];
  const float* bih_f  = (const float*)d_in[5];
  const float* bhh_f  = (const float*)d_in[6];
  const float* Wih_b  = (const float*)d_in[7];
  const float* Whh_b  = (const float*)d_in[8];
  const float* bih_b  = (const float*)d_in[9];
  const float* bhh_b  = (const float*)d_in[10];
  const float* Wp     = (const float*)d_in[11];
  const float* bp     = (const float*)d_in[12];
  const float* trans  = (const float*)d_in[13];
  const float* start_t= (const float*)d_in[14];
  const float* end_t  = (const float*)d_in[15];
  float* out = (float*)d_out;

  char* ws = (char*)d_ws;
  size_t off = 0;
  auto alloc = [&](size_t bytes) { char* p = ws + off; off += (bytes + 255) & ~(size_t)255; return p; };
  __hip_bfloat16* xbf   = (__hip_bfloat16*)alloc((size_t)NM*NE*2);        // 25.2 MB
  __hip_bfloat16* Wihbf = (__hip_bfloat16*)alloc((size_t)1024*NE*2);      // 1.6 MB
  __hip_bfloat16* whhbf = (__hip_bfloat16*)alloc((size_t)2*512*128*2);    // 0.26 MB
  float*          biasp = (float*)alloc(1024*4);
  __hip_bfloat16* xprep = (__hip_bfloat16*)alloc((size_t)2*2*512*8*64*16*2); // 33.6 MB
  float*          hf    = (float*)alloc((size_t)NM*128*4);                // 8.4 MB
  float*          hb    = (float*)alloc((size_t)NM*128*4);                // 8.4 MB
  float*          em    = (float*)alloc((size_t)NM*15*4);                 // 1.0 MB
  float*          nllb  = (float*)alloc(32*4);
  (void)ws_size; (void)in_sizes; (void)n_in; (void)out_size;

  cvt_bf16_kernel<<<2048, 256, 0, stream>>>(x, xbf, NM*NE/4);
  cvt_bf16_kernel<<<256, 256, 0, stream>>>(Wih_f, Wihbf, 512*768/4);
  cvt_bf16_kernel<<<256, 256, 0, stream>>>(Wih_b, Wihbf + 512*768, 512*768/4);
  cvt_bf16_kernel<<<64, 256, 0, stream>>>(Whh_f, whhbf, 512*128/4);
  cvt_bf16_kernel<<<64, 256, 0, stream>>>(Whh_b, whhbf + 512*128, 512*128/4);
  bias_kernel<<<4, 256, 0, stream>>>(bih_f, bhh_f, bih_b, bhh_b, biasp);

  gemm_xproj<<<dim3(128, 8), 256, 0, stream>>>(xbf, Wihbf, biasp, xprep);
  lstm_mfma<<<4, 512, 0, stream>>>(xprep, whhbf, hf, hb);
  em_kernel<<<64, 256, 0, stream>>>(hf, hb, Wp, bp, em);
  crf_kernel<<<32, 64, 0, stream>>>(em, tags, mask, trans, start_t, end_t, nllb);
  nll_reduce_kernel<<<1, 64, 0, stream>>>(nllb, out);
}

// Round 12
// 938.981 us; speedup vs baseline: 1.4558x; 1.4558x over previous
//
#include <hip/hip_runtime.h>
#include <hip/hip_bf16.h>
#include <cstdint>

typedef __attribute__((ext_vector_type(8))) short short8;
typedef __attribute__((ext_vector_type(4))) float f32x4;

#define NS 512
#define NB 32
#define NE 768
#define NH 128
#define NT 15
#define NM (NB*NS)      // 16384 rows, m = b*512 + s

#define LOG2E  1.4426950408889634f
#define LOG2E2 2.8853900817779268f

__device__ __forceinline__ float bflo(unsigned int u){ return __builtin_bit_cast(float, u << 16); }
__device__ __forceinline__ float bfhi(unsigned int u){ return __builtin_bit_cast(float, u & 0xffff0000u); }

__device__ __forceinline__ float rcpf_(float x){
#if __has_builtin(__builtin_amdgcn_rcpf)
  return __builtin_amdgcn_rcpf(x);
#else
  return __fdividef(1.f, x);
#endif
}
__device__ __forceinline__ float ex2_(float x){
#if __has_builtin(__builtin_amdgcn_exp2f)
  return __builtin_amdgcn_exp2f(x);
#else
  return exp2f(x);
#endif
}

// raw workgroup barrier: LDS-drain only, global loads/stores stay in flight.
__device__ __forceinline__ void lds_barrier() {
  asm volatile("s_waitcnt lgkmcnt(0)" ::: "memory");
  __builtin_amdgcn_s_barrier();
  asm volatile("" ::: "memory");
}

__device__ __forceinline__ void gload16(const void* g, void* l) {
#if __has_builtin(__builtin_amdgcn_global_load_lds)
  __builtin_amdgcn_global_load_lds((const __attribute__((address_space(1))) void*)g,
                                   (__attribute__((address_space(3))) void*)l, 16, 0, 0);
#else
  *(uint4*)l = *(const uint4*)g;
#endif
}

// ---------------- converts ----------------
__global__ void cvt_bf16_kernel(const float* __restrict__ in,
                                __hip_bfloat16* __restrict__ out, int n4) {
  int i = blockIdx.x*blockDim.x + threadIdx.x;
  int stride = gridDim.x*blockDim.x;
  for (int j = i; j < n4; j += stride) {
    float4 v = ((const float4*)in)[j];
    ushort4 o;
    o.x = __builtin_bit_cast(unsigned short, __float2bfloat16(v.x));
    o.y = __builtin_bit_cast(unsigned short, __float2bfloat16(v.y));
    o.z = __builtin_bit_cast(unsigned short, __float2bfloat16(v.z));
    o.w = __builtin_bit_cast(unsigned short, __float2bfloat16(v.w));
    ((ushort4*)out)[j] = o;
  }
}

// permuted row n = dir*512 + (j*4+g)  <- src row (g*128+j); PRE-SCALED by gate factor
// (log2e for i,f,o; 2*log2e for g) so activations use exp2 directly.
__global__ void cvt_wih_perm(const float* __restrict__ wf, const float* __restrict__ wb,
                             __hip_bfloat16* __restrict__ out) {
  const int n = blockIdx.x;           // 0..1023
  const int dir = n >> 9, cc = n & 511, j = cc >> 2, g = cc & 3;
  const float fac = (g == 2) ? LOG2E2 : LOG2E;
  const float* src = (dir ? wb : wf) + (size_t)(g*128 + j)*768;
  __hip_bfloat16* dst = out + (size_t)n*768;
  for (int e = threadIdx.x; e < 768; e += 256) dst[e] = __float2bfloat16(src[e]*fac);
}

__global__ void cvt_whh_perm(const float* __restrict__ wf, const float* __restrict__ wb,
                             __hip_bfloat16* __restrict__ out) {
  const int n = blockIdx.x;           // 0..1023 = dir*512+cc
  const int dir = n >> 9, cc = n & 511, j = cc >> 2, g = cc & 3;
  const float fac = (g == 2) ? LOG2E2 : LOG2E;
  const float* src = (dir ? wb : wf) + (size_t)(g*128 + j)*128;
  __hip_bfloat16* dst = out + (size_t)n*128;
  if (threadIdx.x < 128) dst[threadIdx.x] = __float2bfloat16(src[threadIdx.x]*fac);
}

__global__ void bias_perm_kernel(const float* __restrict__ bihf, const float* __restrict__ bhhf,
                                 const float* __restrict__ bihb, const float* __restrict__ bhhb,
                                 float* __restrict__ biasp) {
  const int n = blockIdx.x*blockDim.x + threadIdx.x;
  if (n >= 1024) return;
  const int dir = n >> 9, cc = n & 511, g = cc & 3, j = cc >> 2;
  const float fac = (g == 2) ? LOG2E2 : LOG2E;
  const int src = g*128 + j;
  biasp[n] = fac * (dir ? (bihb[src] + bhhb[src]) : (bihf[src] + bhhf[src]));
}

// ---------------- xproj GEMM: A[16384x768] @ Bw[1024x768]^T -> xqd[2][NM][512] ----------------
__global__ __launch_bounds__(256, 2) void gemm_xproj(
    const __hip_bfloat16* __restrict__ A,
    const __hip_bfloat16* __restrict__ Bw,
    const float* __restrict__ biasp,
    __hip_bfloat16* __restrict__ xqd)        // [2][NM][512] packed j*4+g, scaled
{
  __shared__ __align__(16) __hip_bfloat16 As[128*64];
  __shared__ __align__(16) __hip_bfloat16 Bs[128*64];
  const int bm = blockIdx.x * 128;
  const int bn = blockIdx.y * 128;
  const int tid = threadIdx.x;
  const int lane = tid & 63;
  const int wv = tid >> 6;
  const int wr = wv >> 1, wc = wv & 1;
  char* AsB = (char*)As;
  char* BsB = (char*)Bs;
  const char* Ab = (const char*)A;
  const char* Bb = (const char*)Bw;
  f32x4 acc[4][4] = {};

  for (int kt = 0; kt < 12; ++kt) {
    const int k0 = kt * 64;
    __syncthreads();
    #pragma unroll
    for (int i = 0; i < 4; ++i) {
      int fb = i*4096 + tid*16;
      int r  = fb >> 7;
      int cb = fb & 127;
      gload16(Ab + ((size_t)(bm + r)*768 + k0)*2 + cb, AsB + fb);
      gload16(Bb + ((size_t)(bn + r)*768 + k0)*2 + cb, BsB + fb);
    }
    __syncthreads();
    #pragma unroll
    for (int ks = 0; ks < 2; ++ks) {
      const int krow = ks*32 + ((lane >> 4) << 3);
      short8 af[4], bfr[4];
      #pragma unroll
      for (int m = 0; m < 4; ++m) {
        int row = wr*64 + m*16 + (lane & 15);
        af[m] = *(const short8*)(AsB + (row*64 + krow)*2);
      }
      #pragma unroll
      for (int n = 0; n < 4; ++n) {
        int row = wc*64 + n*16 + (lane & 15);
        bfr[n] = *(const short8*)(BsB + (row*64 + krow)*2);
      }
      #pragma unroll
      for (int m = 0; m < 4; ++m)
        #pragma unroll
        for (int n = 0; n < 4; ++n)
          acc[m][n] = __builtin_amdgcn_mfma_f32_16x16x32_bf16(af[m], bfr[n], acc[m][n], 0, 0, 0);
    }
  }
  #pragma unroll
  for (int m = 0; m < 4; ++m) {
    #pragma unroll
    for (int n = 0; n < 4; ++n) {
      const int col = bn + wc*64 + n*16 + (lane & 15);
      const float bv = biasp[col];
      const int dir = col >> 9;
      const int cc  = col & 511;
      #pragma unroll
      for (int jj = 0; jj < 4; ++jj) {
        const int row = bm + wr*64 + m*16 + ((lane >> 4)*4 + jj);
        xqd[((size_t)dir*NM + row)*512 + cc] = __float2bfloat16(acc[m][n][jj] + bv);
      }
    }
  }
}

// ---------------- LSTM: staggered dual-chain MFMA pipeline ----------------
// 16 blocks = (dir, bg), 4 batches each split into chains P={b0,b1}, Q={b2,b3}
// (same dir -> same Whh). Per interval: MFMA for one chain overlaps activation
// (VALU/trans) for the other. 1 lds_barrier per interval.
//   even interval k: MFMA -> z_P(k) [reads h_P(k-1)];  act: h_Q(k-1) from z_Q(k-1)
//   odd  interval k: MFMA -> z_Q(k) [reads h_Q(k-1)];  act: h_P(k)   from z_P(k)
// hfrag cols: P in batch slots {0,1}, Q in {2,3} (disjoint; stale-col MFMA
// results are discarded via the publish guard). zP/zQ separate buffers.
__global__ __launch_bounds__(512) __attribute__((amdgpu_waves_per_eu(1, 2)))
void lstm_mfma(
    const __hip_bfloat16* __restrict__ xqd,   // [2][NM][512] packed j*4+g, bias folded, scaled
    const __hip_bfloat16* __restrict__ whhp,  // [2][512][128] permuted rows, scaled
    float* __restrict__ hf,                   // [NM][128]
    float* __restrict__ hb)                   // [NM][128]
{
  __shared__ __align__(16) char hfrag[4224];     // [kc:1056B][lane:16B] B-frag layout
  __shared__ __align__(16) float zP[2*520];      // rows b2 of chain P
  __shared__ __align__(16) float zQ[2*520];      // rows b2 of chain Q

  const int bid = blockIdx.x;
  const int dir = bid >> 3, bg = bid & 7;
  const int t = threadIdx.x;
  const int w = t >> 6, l = t & 63;
  const int ln = l & 15, lp = l >> 4;

  // A-fragments (weights): wave w rows (w*4+r)*16+ln, k = kc*32 + lp*8 + e.
  uint4 afu[4][4];
  {
    const char* wbase = (const char*)(whhp + (size_t)dir*512*128);
    #pragma unroll
    for (int r = 0; r < 4; ++r) {
      const int row = (w*4 + r)*16 + ln;
      #pragma unroll
      for (int kc = 0; kc < 4; ++kc)
        afu[r][kc] = *(const uint4*)(wbase + ((size_t)row*128 + lp*8 + kc*32)*2);
    }
  }

  for (int i = t; i < 4224/4; i += 512) ((int*)hfrag)[i] = 0;

  // activation identity (threads 0..255 = waves 0-3; one per SIMD pairs with an MFMA-only wave)
  const bool actw = (t < 256);
  const int b2 = t & 1, j = (t >> 1) & 127;
  const int jsw = j ^ ((j >> 3) & 7);
  const int woffP = (j >> 5)*1056 + ((j >> 3) & 3)*256 + b2*16 + (j & 7)*2;
  const int woffQ = woffP + 2*16;
  const int bP = bg*4 + b2, bQ = bg*4 + 2 + b2;
  const int sdir = dir ? -1 : 1;
  const int s0 = dir ? 511 : 0;
  const __hip_bfloat16* xbP = xqd + ((size_t)dir*NM + (size_t)bP*512)*512 + j*4;
  const __hip_bfloat16* xbQ = xqd + ((size_t)dir*NM + (size_t)bQ*512)*512 + j*4;
  float* pHP = (dir ? hb : hf) + (size_t)bP*512*128 + (size_t)s0*128 + j;
  float* pHQ = (dir ? hb : hf) + (size_t)bQ*512*128 + (size_t)s0*128 + j;
  const ptrdiff_t hstride = (ptrdiff_t)sdir*128;
  const ptrdiff_t xstride = (ptrdiff_t)sdir*512;

  uint2 xPc{}, xPn{}, xQc{}, xQn{};
  const __hip_bfloat16* pxP = xbP + (ptrdiff_t)(2*sdir)*512 + (ptrdiff_t)s0*512;
  const __hip_bfloat16* pxQ = xbQ + (ptrdiff_t)(2*sdir)*512 + (ptrdiff_t)s0*512;
  if (actw) {
    xPc = *(const uint2*)(xbP + (ptrdiff_t)s0*512);
    xPn = *(const uint2*)(xbP + (ptrdiff_t)(s0 + sdir)*512);
    xQc = *(const uint2*)(xbQ + (ptrdiff_t)s0*512);
    xQn = *(const uint2*)(xbQ + (ptrdiff_t)(s0 + sdir)*512);
  }
  float cP = 0.f, cQ = 0.f;

  // activation: z' pre-scaled (log2e / 2log2e) -> exp2 forms
  auto ACT = [&](const float* zb, uint2 xu, float& c, int woff, float* ph) {
    const f32x4 zv = *(const f32x4*)&zb[b2*520 + 4*jsw];
    const float zi = zv[0] + bflo(xu.x);
    const float zf = zv[1] + bfhi(xu.x);
    const float zg = zv[2] + bflo(xu.y);
    const float zo = zv[3] + bfhi(xu.y);
    const float I = rcpf_(1.f + ex2_(-zi));
    const float F = rcpf_(1.f + ex2_(-zf));
    const float G = 1.f - 2.f*rcpf_(ex2_(zg) + 1.f);
    const float O = rcpf_(1.f + ex2_(-zo));
    c = F*c + I*G;
    const float tc = 1.f - 2.f*rcpf_(ex2_(c*LOG2E2) + 1.f);
    const float h = O*tc;
    *(short*)(hfrag + woff) = (short)__builtin_bit_cast(unsigned short, __float2bfloat16(h));
    *ph = h;
  };

  auto MFMA_PUB = [&](float* zbuf, int lnLo) {
    short8 bfv[4];
    #pragma unroll
    for (int kc = 0; kc < 4; ++kc)
      bfv[kc] = *(const short8*)(hfrag + kc*1056 + l*16);
    f32x4 acc[4];
    #pragma unroll
    for (int r = 0; r < 4; ++r) {
      acc[r] = f32x4{0.f, 0.f, 0.f, 0.f};
      #pragma unroll
      for (int kc = 0; kc < 4; ++kc)
        acc[r] = __builtin_amdgcn_mfma_f32_16x16x32_bf16(
                   __builtin_bit_cast(short8, afu[r][kc]), bfv[kc], acc[r], 0, 0, 0);
    }
    if (ln >= lnLo && ln < lnLo + 2) {
      #pragma unroll
      for (int r = 0; r < 4; ++r) {
        const int jw = (w*4 + r)*4 + lp;
        const int js = jw ^ ((jw >> 3) & 7);
        *(f32x4*)&zbuf[(ln - lnLo)*520 + 4*js] = acc[r];
      }
    }
  };

  __syncthreads();   // prologue only

  for (int kc2 = 0; kc2 < 64; ++kc2) {
    // AGPR pin (R9-proven residency mechanism)
    #pragma unroll
    for (int r = 0; r < 4; ++r)
      #pragma unroll
      for (int kc = 0; kc < 4; ++kc)
        asm volatile("" : "+a"(afu[r][kc].x), "+a"(afu[r][kc].y),
                          "+a"(afu[r][kc].z), "+a"(afu[r][kc].w));

    for (int kk = 0; kk < 8; ++kk) {
      const int k = kc2*8 + kk;

      // ===== even interval: MFMA -> z_P(k) ; act h_Q(k-1) =====
      if (actw && k > 0) {
        ACT(zQ, xQc, cQ, woffQ, pHQ);
        pHQ += hstride;
        xQc = xQn;
        if (k + 1 <= 511) { xQn = *(const uint2*)pxQ; pxQ += xstride; }
      }
      MFMA_PUB(zP, 0);
      lds_barrier();

      // ===== odd interval: MFMA -> z_Q(k) ; act h_P(k) =====
      if (actw) {
        ACT(zP, xPc, cP, woffP, pHP);
        pHP += hstride;
        xPc = xPn;
        if (k + 2 <= 511) { xPn = *(const uint2*)pxP; pxP += xstride; }
      }
      MFMA_PUB(zQ, 2);
      lds_barrier();
    }
  }
  // epilogue: act h_Q(511)
  if (actw) ACT(zQ, xQc, cQ, woffQ, pHQ);
}

// ---------------- emissions: em[m][t] = [hf|hb][m] . Wp[t] + bp[t] ----------------
__global__ __launch_bounds__(256) void em_kernel(
    const float* __restrict__ hf, const float* __restrict__ hb,
    const float* __restrict__ Wp, const float* __restrict__ bp,
    float* __restrict__ em)
{
  __shared__ float wps[15*256];
  __shared__ float bps[15];
  const int tid = threadIdx.x;
  for (int i = tid; i < 15*256; i += 256) wps[i] = Wp[i];
  if (tid < 15) bps[tid] = bp[tid];
  __syncthreads();
  const size_t m = (size_t)blockIdx.x*256 + tid;
  float acc[15];
  #pragma unroll
  for (int t2 = 0; t2 < 15; ++t2) acc[t2] = bps[t2];
  const float4* hf4 = (const float4*)(hf + m*128);
  const float4* hb4 = (const float4*)(hb + m*128);
  for (int kc = 0; kc < 32; ++kc) {
    float4 hv = hf4[kc];
    #pragma unroll
    for (int t2 = 0; t2 < 15; ++t2)
      acc[t2] += hv.x*wps[t2*256 + kc*4+0] + hv.y*wps[t2*256 + kc*4+1]
               + hv.z*wps[t2*256 + kc*4+2] + hv.w*wps[t2*256 + kc*4+3];
  }
  for (int kc = 0; kc < 32; ++kc) {
    float4 hv = hb4[kc];
    #pragma unroll
    for (int t2 = 0; t2 < 15; ++t2)
      acc[t2] += hv.x*wps[t2*256 + 128 + kc*4+0] + hv.y*wps[t2*256 + 128 + kc*4+1]
               + hv.z*wps[t2*256 + 128 + kc*4+2] + hv.w*wps[t2*256 + 128 + kc*4+3];
  }
  float* eo = em + m*15;
  #pragma unroll
  for (int t2 = 0; t2 < 15; ++t2) eo[t2] = acc[t2];
}

// ---------------- CRF NLL: one block (1 wave) per batch -> partial per b ----------------
__global__ __launch_bounds__(64) void crf_kernel(
    const float* __restrict__ em,
    const int* __restrict__ tags, const int* __restrict__ mask,
    const float* __restrict__ trans, const float* __restrict__ start_t,
    const float* __restrict__ end_t, float* __restrict__ nllb)
{
  __shared__ __align__(16) float ems[512*15];
  __shared__ float trs[225];
  __shared__ int tgs[512];
  __shared__ int mks[512];
  const int b = blockIdx.x, j = threadIdx.x;
  const float* emb = em + (size_t)b*512*15;
  {
    const float4* s4 = (const float4*)emb;
    float4* d4 = (float4*)ems;
    for (int i = j; i < 512*15/4; i += 64) d4[i] = s4[i];
    for (int i = j; i < 512; i += 64) { tgs[i] = tags[b*512+i]; mks[i] = mask[b*512+i]; }
    for (int i = j; i < 225; i += 64) trs[i] = trans[i];
  }
  __syncthreads();

  float trc[15];
  #pragma unroll
  for (int i = 0; i < 15; ++i) trc[i] = (j < 15) ? trs[i*15 + j] : 0.f;

  float alpha = (j < 15) ? (start_t[j] + ems[j]) : -3.0e38f;
  for (int s = 1; s < 512; ++s) {
    const float emv = (j < 15) ? ems[s*15 + j] : 0.f;
    const int msk = mks[s];
    float v[15];
    #pragma unroll
    for (int i = 0; i < 15; ++i) {
      const float ai = __shfl(alpha, i, 64);
      v[i] = ai + trc[i];
    }
    const float t01 = fmaxf(v[0], v[1]),  t23 = fmaxf(v[2], v[3]);
    const float t45 = fmaxf(v[4], v[5]),  t67 = fmaxf(v[6], v[7]);
    const float t89 = fmaxf(v[8], v[9]),  tab = fmaxf(v[10], v[11]);
    const float tcd = fmaxf(v[12], v[13]);
    const float q0 = fmaxf(t01, t23), q1 = fmaxf(t45, t67);
    const float q2 = fmaxf(t89, tab), q3 = fmaxf(tcd, v[14]);
    const float mx = fmaxf(fmaxf(q0, q1), fmaxf(q2, q3));
    float e[15];
    #pragma unroll
    for (int i = 0; i < 15; ++i) e[i] = __expf(v[i] - mx);
    const float s01 = e[0]+e[1], s23 = e[2]+e[3], s45 = e[4]+e[5], s67 = e[6]+e[7];
    const float s89 = e[8]+e[9], sab = e[10]+e[11], scd = e[12]+e[13];
    const float u0 = s01+s23, u1 = s45+s67, u2 = s89+sab, u3 = scd+e[14];
    const float sum = (u0+u1) + (u2+u3);
    const float nxt = emv + mx + __logf(sum);
    if (msk > 0 && j < 15) alpha = nxt;
  }
  float vz = (j < 15) ? (alpha + end_t[j]) : -3.0e38f;
  float mz = vz;
  #pragma unroll
  for (int off = 32; off > 0; off >>= 1) mz = fmaxf(mz, __shfl_xor(mz, off, 64));
  float se = (j < 15) ? __expf(vz - mz) : 0.f;
  #pragma unroll
  for (int off = 32; off > 0; off >>= 1) se += __shfl_xor(se, off, 64);
  const float logZ = mz + __logf(se);

  float sc = 0.f; int cnt = 0;
  for (int s = j; s < 512; s += 64) cnt += (mks[s] ? 1 : 0);
  for (int s = 1 + j; s < 512; s += 64) {
    if (mks[s]) {
      const int tp = tgs[s-1], tc = tgs[s];
      sc += trs[tp*15 + tc] + ems[s*15 + tc];
    }
  }
  #pragma unroll
  for (int off = 32; off > 0; off >>= 1) {
    sc  += __shfl_xor(sc, off, 64);
    cnt += __shfl_xor(cnt, off, 64);
  }
  if (j == 0) {
    const int t0 = tgs[0];
    sc += start_t[t0] + ems[t0];
    int last = cnt - 1; if (last < 0) last = 0;
    sc += end_t[tgs[last]];
    nllb[b] = logZ - sc;
  }
}

__global__ __launch_bounds__(64) void nll_reduce_kernel(const float* __restrict__ nllb,
                                                        float* __restrict__ out) {
  const int j = threadIdx.x;
  float v = (j < 32) ? nllb[j] : 0.f;
  #pragma unroll
  for (int off = 32; off > 0; off >>= 1) v += __shfl_xor(v, off, 64);
  if (j == 0) out[0] = v;
}

// ---------------- launch ----------------
extern "C" void kernel_launch(void* const* d_in, const int* in_sizes, int n_in,
                              void* d_out, int out_size, void* d_ws, size_t ws_size,
                              hipStream_t stream) {
  const float* x      = (const float*)d_in[0];
  const int*   tags   = (const int*)d_in[1];
  const int*   mask   = (const int*)d_in[2];
  const float* Wih_f  = (const float*)d_in[3];
  const float* Whh_f  = (const float*)d_in[4];
  const float* bih_f  = (const float*)d_in[5];
  const float* bhh_f  = (const float*)d_in[6];
  const float* Wih_b  = (const float*)d_in[7];
  const float* Whh_b  = (const float*)d_in[8];
  const float* bih_b  = (const float*)d_in[9];
  const float* bhh_b  = (const float*)d_in[10];
  const float* Wp     = (const float*)d_in[11];
  const float* bp     = (const float*)d_in[12];
  const float* trans  = (const float*)d_in[13];
  const float* start_t= (const float*)d_in[14];
  const float* end_t  = (const float*)d_in[15];
  float* out = (float*)d_out;

  char* ws = (char*)d_ws;
  size_t off = 0;
  auto alloc = [&](size_t bytes) { char* p = ws + off; off += (bytes + 255) & ~(size_t)255; return p; };
  __hip_bfloat16* xbf   = (__hip_bfloat16*)alloc((size_t)NM*NE*2);        // 25.2 MB
  __hip_bfloat16* Wihbf = (__hip_bfloat16*)alloc((size_t)1024*NE*2);      // 1.6 MB
  __hip_bfloat16* whhp  = (__hip_bfloat16*)alloc((size_t)2*512*128*2);    // 0.26 MB
  float*          biasp = (float*)alloc(1024*4);
  __hip_bfloat16* xqd   = (__hip_bfloat16*)alloc((size_t)2*NM*512*2);     // 33.6 MB
  float*          hf    = (float*)alloc((size_t)NM*128*4);                // 8.4 MB
  float*          hb    = (float*)alloc((size_t)NM*128*4);                // 8.4 MB
  float*          em    = (float*)alloc((size_t)NM*15*4);                 // 1.0 MB
  float*          nllb  = (float*)alloc(32*4);
  (void)ws_size; (void)in_sizes; (void)n_in; (void)out_size;

  cvt_bf16_kernel<<<2048, 256, 0, stream>>>(x, xbf, NM*NE/4);
  cvt_wih_perm<<<1024, 256, 0, stream>>>(Wih_f, Wih_b, Wihbf);
  cvt_whh_perm<<<1024, 128, 0, stream>>>(Whh_f, Whh_b, whhp);
  bias_perm_kernel<<<4, 256, 0, stream>>>(bih_f, bhh_f, bih_b, bhh_b, biasp);

  gemm_xproj<<<dim3(128, 8), 256, 0, stream>>>(xbf, Wihbf, biasp, xqd);
  lstm_mfma<<<16, 512, 0, stream>>>(xqd, whhp, hf, hb);
  em_kernel<<<64, 256, 0, stream>>>(hf, hb, Wp, bp, em);
  crf_kernel<<<32, 64, 0, stream>>>(em, tags, mask, trans, start_t, end_t, nllb);
  nll_reduce_kernel<<<1, 64, 0, stream>>>(nllb, out);
}

// Round 13
// 610.605 us; speedup vs baseline: 2.2388x; 1.5378x over previous
//
#include <hip/hip_runtime.h>
#include <hip/hip_bf16.h>
#include <cstdint>

typedef __attribute__((ext_vector_type(8))) short short8;
typedef __attribute__((ext_vector_type(4))) float f32x4;

#define NS 512
#define NB 32
#define NE 768
#define NH 128
#define NT 15
#define NM (NB*NS)      // 16384 rows, m = b*512 + s

#define LOG2E  1.4426950408889634f
#define LOG2E2 2.8853900817779268f

__device__ __forceinline__ float bflo(unsigned int u){ return __builtin_bit_cast(float, u << 16); }
__device__ __forceinline__ float bfhi(unsigned int u){ return __builtin_bit_cast(float, u & 0xffff0000u); }

__device__ __forceinline__ float rcpf_(float x){
#if __has_builtin(__builtin_amdgcn_rcpf)
  return __builtin_amdgcn_rcpf(x);
#else
  return __fdividef(1.f, x);
#endif
}
__device__ __forceinline__ float ex2_(float x){
#if __has_builtin(__builtin_amdgcn_exp2f)
  return __builtin_amdgcn_exp2f(x);
#else
  return exp2f(x);
#endif
}

// raw workgroup barrier: LDS-drain only, global loads/stores stay in flight.
__device__ __forceinline__ void lds_barrier() {
  asm volatile("s_waitcnt lgkmcnt(0)" ::: "memory");
  __builtin_amdgcn_s_barrier();
  asm volatile("" ::: "memory");
}

__device__ __forceinline__ void gload16(const void* g, void* l) {
#if __has_builtin(__builtin_amdgcn_global_load_lds)
  __builtin_amdgcn_global_load_lds((const __attribute__((address_space(1))) void*)g,
                                   (__attribute__((address_space(3))) void*)l, 16, 0, 0);
#else
  *(uint4*)l = *(const uint4*)g;
#endif
}

// ---------------- converts ----------------
__global__ void cvt_bf16_kernel(const float* __restrict__ in,
                                __hip_bfloat16* __restrict__ out, int n4) {
  int i = blockIdx.x*blockDim.x + threadIdx.x;
  int stride = gridDim.x*blockDim.x;
  for (int j = i; j < n4; j += stride) {
    float4 v = ((const float4*)in)[j];
    ushort4 o;
    o.x = __builtin_bit_cast(unsigned short, __float2bfloat16(v.x));
    o.y = __builtin_bit_cast(unsigned short, __float2bfloat16(v.y));
    o.z = __builtin_bit_cast(unsigned short, __float2bfloat16(v.z));
    o.w = __builtin_bit_cast(unsigned short, __float2bfloat16(v.w));
    ((ushort4*)out)[j] = o;
  }
}

// permuted row n = dir*512 + (j*4+g)  <- src row (g*128+j); PRE-SCALED by gate factor
// (log2e for i,f,o; 2*log2e for g) so activations use exp2 directly.
__global__ void cvt_wih_perm(const float* __restrict__ wf, const float* __restrict__ wb,
                             __hip_bfloat16* __restrict__ out) {
  const int n = blockIdx.x;           // 0..1023
  const int dir = n >> 9, cc = n & 511, j = cc >> 2, g = cc & 3;
  const float fac = (g == 2) ? LOG2E2 : LOG2E;
  const float* src = (dir ? wb : wf) + (size_t)(g*128 + j)*768;
  __hip_bfloat16* dst = out + (size_t)n*768;
  for (int e = threadIdx.x; e < 768; e += 256) dst[e] = __float2bfloat16(src[e]*fac);
}

__global__ void cvt_whh_perm(const float* __restrict__ wf, const float* __restrict__ wb,
                             __hip_bfloat16* __restrict__ out) {
  const int n = blockIdx.x;           // 0..1023 = dir*512+cc
  const int dir = n >> 9, cc = n & 511, j = cc >> 2, g = cc & 3;
  const float fac = (g == 2) ? LOG2E2 : LOG2E;
  const float* src = (dir ? wb : wf) + (size_t)(g*128 + j)*128;
  __hip_bfloat16* dst = out + (size_t)n*128;
  if (threadIdx.x < 128) dst[threadIdx.x] = __float2bfloat16(src[threadIdx.x]*fac);
}

__global__ void bias_perm_kernel(const float* __restrict__ bihf, const float* __restrict__ bhhf,
                                 const float* __restrict__ bihb, const float* __restrict__ bhhb,
                                 float* __restrict__ biasp) {
  const int n = blockIdx.x*blockDim.x + threadIdx.x;
  if (n >= 1024) return;
  const int dir = n >> 9, cc = n & 511, g = cc & 3, j = cc >> 2;
  const float fac = (g == 2) ? LOG2E2 : LOG2E;
  const int src = g*128 + j;
  biasp[n] = fac * (dir ? (bihb[src] + bhhb[src]) : (bihf[src] + bhhf[src]));
}

// ---------------- xproj GEMM: A[16384x768] @ Bw[1024x768]^T -> xqd[2][NM][512] ----------------
__global__ __launch_bounds__(256, 2) void gemm_xproj(
    const __hip_bfloat16* __restrict__ A,
    const __hip_bfloat16* __restrict__ Bw,
    const float* __restrict__ biasp,
    __hip_bfloat16* __restrict__ xqd)        // [2][NM][512] packed j*4+g, scaled
{
  __shared__ __align__(16) __hip_bfloat16 As[128*64];
  __shared__ __align__(16) __hip_bfloat16 Bs[128*64];
  const int bm = blockIdx.x * 128;
  const int bn = blockIdx.y * 128;
  const int tid = threadIdx.x;
  const int lane = tid & 63;
  const int wv = tid >> 6;
  const int wr = wv >> 1, wc = wv & 1;
  char* AsB = (char*)As;
  char* BsB = (char*)Bs;
  const char* Ab = (const char*)A;
  const char* Bb = (const char*)Bw;
  f32x4 acc[4][4] = {};

  for (int kt = 0; kt < 12; ++kt) {
    const int k0 = kt * 64;
    __syncthreads();
    #pragma unroll
    for (int i = 0; i < 4; ++i) {
      int fb = i*4096 + tid*16;
      int r  = fb >> 7;
      int cb = fb & 127;
      gload16(Ab + ((size_t)(bm + r)*768 + k0)*2 + cb, AsB + fb);
      gload16(Bb + ((size_t)(bn + r)*768 + k0)*2 + cb, BsB + fb);
    }
    __syncthreads();
    #pragma unroll
    for (int ks = 0; ks < 2; ++ks) {
      const int krow = ks*32 + ((lane >> 4) << 3);
      short8 af[4], bfr[4];
      #pragma unroll
      for (int m = 0; m < 4; ++m) {
        int row = wr*64 + m*16 + (lane & 15);
        af[m] = *(const short8*)(AsB + (row*64 + krow)*2);
      }
      #pragma unroll
      for (int n = 0; n < 4; ++n) {
        int row = wc*64 + n*16 + (lane & 15);
        bfr[n] = *(const short8*)(BsB + (row*64 + krow)*2);
      }
      #pragma unroll
      for (int m = 0; m < 4; ++m)
        #pragma unroll
        for (int n = 0; n < 4; ++n)
          acc[m][n] = __builtin_amdgcn_mfma_f32_16x16x32_bf16(af[m], bfr[n], acc[m][n], 0, 0, 0);
    }
  }
  #pragma unroll
  for (int m = 0; m < 4; ++m) {
    #pragma unroll
    for (int n = 0; n < 4; ++n) {
      const int col = bn + wc*64 + n*16 + (lane & 15);
      const float bv = biasp[col];
      const int dir = col >> 9;
      const int cc  = col & 511;
      #pragma unroll
      for (int jj = 0; jj < 4; ++jj) {
        const int row = bm + wr*64 + m*16 + ((lane >> 4)*4 + jj);
        xqd[((size_t)dir*NM + row)*512 + cc] = __float2bfloat16(acc[m][n][jj] + bv);
      }
    }
  }
}

// ---------------- LSTM: R9 two-phase structure, register-lean x pipeline ----------------
// 16 blocks = (dir, bg), 4 batches each, 512 threads = 8 waves.
// Phase A: z[512x16] = Whhp @ h via MFMA (weights AGPR-pinned); z -> swizzled z_lds.
// Phase B: thread (b4=t&3, j=t>>2) computes one h; h -> next B-frag buffer + global.
// x: depth-4 rotating registers (8 VGPRs total), fetch-into-consumed-slot,
// pointer-stride addressing. 127 x 4-step steady-state + 4-step epilogue.
__global__ __launch_bounds__(512) __attribute__((amdgpu_waves_per_eu(1, 2)))
void lstm_mfma(
    const __hip_bfloat16* __restrict__ xqd,   // [2][NM][512] packed j*4+g, bias folded, scaled
    const __hip_bfloat16* __restrict__ whhp,  // [2][512][128] permuted rows, scaled
    float* __restrict__ hf,                   // [NM][128]
    float* __restrict__ hb)                   // [NM][128]
{
  __shared__ __align__(16) char hfrag[2*4224];   // [buf][kc:1056B][lane:16B] B-frag layout
  __shared__ __align__(16) float z_lds[4*520];   // [b][4*swz(j)] f32x4, swizzled

  const int bid = blockIdx.x;
  const int dir = bid >> 3, bg = bid & 7;
  const int t = threadIdx.x;
  const int w = t >> 6, l = t & 63;
  const int ln = l & 15, lp = l >> 4;

  // A-fragments (weights): wave w rows (w*4+r)*16+ln, k = kc*32 + lp*8 + e.
  uint4 afu[4][4];
  {
    const char* wbase = (const char*)(whhp + (size_t)dir*512*128);
    #pragma unroll
    for (int r = 0; r < 4; ++r) {
      const int row = (w*4 + r)*16 + ln;
      #pragma unroll
      for (int kc = 0; kc < 4; ++kc)
        afu[r][kc] = *(const uint4*)(wbase + ((size_t)row*128 + lp*8 + kc*32)*2);
    }
  }

  for (int i = t; i < 2*4224/4; i += 512) ((int*)hfrag)[i] = 0;

  // phase-B identity
  const int b4 = t & 3, j = t >> 2;
  const int bsafe = bg*4 + b4;
  const int jsw = j ^ ((j >> 3) & 7);
  const int woff = (j >> 5)*1056 + ((j >> 3) & 3)*256 + b4*16 + (j & 7)*2;
  const int sdir = dir ? -1 : 1;
  const int s0 = dir ? 511 : 0;
  const ptrdiff_t xstep = (ptrdiff_t)sdir*512;
  const ptrdiff_t hstep = (ptrdiff_t)sdir*128;
  const __hip_bfloat16* xbase = xqd + ((size_t)dir*NM + (size_t)bsafe*512)*512
                                + (ptrdiff_t)s0*512 + j*4;
  float* hout = (dir ? hb : hf) + (size_t)bsafe*512*128 + (ptrdiff_t)s0*128 + j;

  float c = 0.f;

  // depth-4 rotating x registers
  uint2 x0 = *(const uint2*)(xbase);
  uint2 x1 = *(const uint2*)(xbase + xstep);
  uint2 x2 = *(const uint2*)(xbase + 2*xstep);
  uint2 x3 = *(const uint2*)(xbase + 3*xstep);
  const __hip_bfloat16* xpre = xbase + 4*xstep;   // next address to fetch
  __syncthreads();   // prologue only

  int buf = 0;

  auto STEP = [&](uint2& xc, bool pf) {
    // ---- phase A: B-fragments (lane-linear, conflict-free) + 16 MFMA ----
    short8 bfv[4];
    #pragma unroll
    for (int kc = 0; kc < 4; ++kc)
      bfv[kc] = *(const short8*)(hfrag + buf*4224 + kc*1056 + l*16);

    f32x4 acc[4];
    #pragma unroll
    for (int r = 0; r < 4; ++r) {
      acc[r] = f32x4{0.f, 0.f, 0.f, 0.f};
      #pragma unroll
      for (int kc = 0; kc < 4; ++kc)
        acc[r] = __builtin_amdgcn_mfma_f32_16x16x32_bf16(
                   __builtin_bit_cast(short8, afu[r][kc]), bfv[kc], acc[r], 0, 0, 0);
    }

    // issue x refill for step s+4 into the slot being consumed (in flight across barriers)
    uint2 xn;
    if (pf) xn = *(const uint2*)xpre;

    // publish z (real batch cols ln<4 only), XOR-swizzled -> conflict-free
    if (ln < 4) {
      #pragma unroll
      for (int r = 0; r < 4; ++r) {
        const int jw = (w*4 + r)*4 + lp;
        const int js = jw ^ ((jw >> 3) & 7);
        *(f32x4*)&z_lds[ln*520 + 4*js] = acc[r];
      }
    }
    lds_barrier();

    // ---- phase B: one h per thread (exp2 forms, inputs pre-scaled) ----
    const f32x4 zv = *(const f32x4*)&z_lds[b4*520 + 4*jsw];
    const float zi = zv[0] + bflo(xc.x);
    const float zf = zv[1] + bfhi(xc.x);
    const float zg = zv[2] + bflo(xc.y);
    const float zo = zv[3] + bfhi(xc.y);
    const float I = rcpf_(1.f + ex2_(-zi));
    const float F = rcpf_(1.f + ex2_(-zf));
    const float G = 1.f - 2.f*rcpf_(ex2_(zg) + 1.f);
    const float O = rcpf_(1.f + ex2_(-zo));
    c = F*c + I*G;
    const float h = O*(1.f - 2.f*rcpf_(ex2_(c*LOG2E2) + 1.f));

    *(short*)(hfrag + (buf ^ 1)*4224 + woff) =
        (short)__builtin_bit_cast(unsigned short, __float2bfloat16(h));
    *hout = h;                         // fire-and-forget (never drained in-loop)
    hout += hstep;
    if (pf) { xc = xn; xpre += xstep; }
    lds_barrier();
    buf ^= 1;
  };

  for (int it = 0; it < 127; ++it) {   // 508 steps with prefetch
    // AGPR pin (R9-proven residency mechanism)
    #pragma unroll
    for (int r = 0; r < 4; ++r)
      #pragma unroll
      for (int kc = 0; kc < 4; ++kc)
        asm volatile("" : "+a"(afu[r][kc].x), "+a"(afu[r][kc].y),
                          "+a"(afu[r][kc].z), "+a"(afu[r][kc].w));
    STEP(x0, true);
    STEP(x1, true);
    STEP(x2, true);
    STEP(x3, true);
  }
  // epilogue: last 4 steps, no prefetch
  STEP(x0, false);
  STEP(x1, false);
  STEP(x2, false);
  STEP(x3, false);
}

// ---------------- emissions: em[m][t] = [hf|hb][m] . Wp[t] + bp[t] ----------------
__global__ __launch_bounds__(256) void em_kernel(
    const float* __restrict__ hf, const float* __restrict__ hb,
    const float* __restrict__ Wp, const float* __restrict__ bp,
    float* __restrict__ em)
{
  __shared__ float wps[15*256];
  __shared__ float bps[15];
  const int tid = threadIdx.x;
  for (int i = tid; i < 15*256; i += 256) wps[i] = Wp[i];
  if (tid < 15) bps[tid] = bp[tid];
  __syncthreads();
  const size_t m = (size_t)blockIdx.x*256 + tid;
  float acc[15];
  #pragma unroll
  for (int t2 = 0; t2 < 15; ++t2) acc[t2] = bps[t2];
  const float4* hf4 = (const float4*)(hf + m*128);
  const float4* hb4 = (const float4*)(hb + m*128);
  for (int kc = 0; kc < 32; ++kc) {
    float4 hv = hf4[kc];
    #pragma unroll
    for (int t2 = 0; t2 < 15; ++t2)
      acc[t2] += hv.x*wps[t2*256 + kc*4+0] + hv.y*wps[t2*256 + kc*4+1]
               + hv.z*wps[t2*256 + kc*4+2] + hv.w*wps[t2*256 + kc*4+3];
  }
  for (int kc = 0; kc < 32; ++kc) {
    float4 hv = hb4[kc];
    #pragma unroll
    for (int t2 = 0; t2 < 15; ++t2)
      acc[t2] += hv.x*wps[t2*256 + 128 + kc*4+0] + hv.y*wps[t2*256 + 128 + kc*4+1]
               + hv.z*wps[t2*256 + 128 + kc*4+2] + hv.w*wps[t2*256 + 128 + kc*4+3];
  }
  float* eo = em + m*15;
  #pragma unroll
  for (int t2 = 0; t2 < 15; ++t2) eo[t2] = acc[t2];
}

// ---------------- CRF NLL: one block (1 wave) per batch -> partial per b ----------------
__global__ __launch_bounds__(64) void crf_kernel(
    const float* __restrict__ em,
    const int* __restrict__ tags, const int* __restrict__ mask,
    const float* __restrict__ trans, const float* __restrict__ start_t,
    const float* __restrict__ end_t, float* __restrict__ nllb)
{
  __shared__ __align__(16) float ems[512*15];
  __shared__ float trs[225];
  __shared__ int tgs[512];
  __shared__ int mks[512];
  const int b = blockIdx.x, j = threadIdx.x;
  const float* emb = em + (size_t)b*512*15;
  {
    const float4* s4 = (const float4*)emb;
    float4* d4 = (float4*)ems;
    for (int i = j; i < 512*15/4; i += 64) d4[i] = s4[i];
    for (int i = j; i < 512; i += 64) { tgs[i] = tags[b*512+i]; mks[i] = mask[b*512+i]; }
    for (int i = j; i < 225; i += 64) trs[i] = trans[i];
  }
  __syncthreads();

  float trc[15];
  #pragma unroll
  for (int i = 0; i < 15; ++i) trc[i] = (j < 15) ? trs[i*15 + j] : 0.f;

  float alpha = (j < 15) ? (start_t[j] + ems[j]) : -3.0e38f;
  for (int s = 1; s < 512; ++s) {
    const float emv = (j < 15) ? ems[s*15 + j] : 0.f;
    const int msk = mks[s];
    float v[15];
    #pragma unroll
    for (int i = 0; i < 15; ++i) {
      const float ai = __shfl(alpha, i, 64);
      v[i] = ai + trc[i];
    }
    const float t01 = fmaxf(v[0], v[1]),  t23 = fmaxf(v[2], v[3]);
    const float t45 = fmaxf(v[4], v[5]),  t67 = fmaxf(v[6], v[7]);
    const float t89 = fmaxf(v[8], v[9]),  tab = fmaxf(v[10], v[11]);
    const float tcd = fmaxf(v[12], v[13]);
    const float q0 = fmaxf(t01, t23), q1 = fmaxf(t45, t67);
    const float q2 = fmaxf(t89, tab), q3 = fmaxf(tcd, v[14]);
    const float mx = fmaxf(fmaxf(q0, q1), fmaxf(q2, q3));
    float e[15];
    #pragma unroll
    for (int i = 0; i < 15; ++i) e[i] = __expf(v[i] - mx);
    const float s01 = e[0]+e[1], s23 = e[2]+e[3], s45 = e[4]+e[5], s67 = e[6]+e[7];
    const float s89 = e[8]+e[9], sab = e[10]+e[11], scd = e[12]+e[13];
    const float u0 = s01+s23, u1 = s45+s67, u2 = s89+sab, u3 = scd+e[14];
    const float sum = (u0+u1) + (u2+u3);
    const float nxt = emv + mx + __logf(sum);
    if (msk > 0 && j < 15) alpha = nxt;
  }
  float vz = (j < 15) ? (alpha + end_t[j]) : -3.0e38f;
  float mz = vz;
  #pragma unroll
  for (int off = 32; off > 0; off >>= 1) mz = fmaxf(mz, __shfl_xor(mz, off, 64));
  float se = (j < 15) ? __expf(vz - mz) : 0.f;
  #pragma unroll
  for (int off = 32; off > 0; off >>= 1) se += __shfl_xor(se, off, 64);
  const float logZ = mz + __logf(se);

  float sc = 0.f; int cnt = 0;
  for (int s = j; s < 512; s += 64) cnt += (mks[s] ? 1 : 0);
  for (int s = 1 + j; s < 512; s += 64) {
    if (mks[s]) {
      const int tp = tgs[s-1], tc = tgs[s];
      sc += trs[tp*15 + tc] + ems[s*15 + tc];
    }
  }
  #pragma unroll
  for (int off = 32; off > 0; off >>= 1) {
    sc  += __shfl_xor(sc, off, 64);
    cnt += __shfl_xor(cnt, off, 64);
  }
  if (j == 0) {
    const int t0 = tgs[0];
    sc += start_t[t0] + ems[t0];
    int last = cnt - 1; if (last < 0) last = 0;
    sc += end_t[tgs[last]];
    nllb[b] = logZ - sc;
  }
}

__global__ __launch_bounds__(64) void nll_reduce_kernel(const float* __restrict__ nllb,
                                                        float* __restrict__ out) {
  const int j = threadIdx.x;
  float v = (j < 32) ? nllb[j] : 0.f;
  #pragma unroll
  for (int off = 32; off > 0; off >>= 1) v += __shfl_xor(v, off, 64);
  if (j == 0) out[0] = v;
}

// ---------------- launch ----------------
extern "C" void kernel_launch(void* const* d_in, const int* in_sizes, int n_in,
                              void* d_out, int out_size, void* d_ws, size_t ws_size,
                              hipStream_t stream) {
  const float* x      = (const float*)d_in[0];
  const int*   tags   = (const int*)d_in[1];
  const int*   mask   = (const int*)d_in[2];
  const float* Wih_f  = (const float*)d_in[3];
  const float* Whh_f  = (const float*)d_in[4];
  const float* bih_f  = (const float*)d_in[5];
  const float* bhh_f  = (const float*)d_in[6];
  const float* Wih_b  = (const float*)d_in[7];
  const float* Whh_b  = (const float*)d_in[8];
  const float* bih_b  = (const float*)d_in[9];
  const float* bhh_b  = (const float*)d_in[10];
  const float* Wp     = (const float*)d_in[11];
  const float* bp     = (const float*)d_in[12];
  const float* trans  = (const float*)d_in[13];
  const float* start_t= (const float*)d_in[14];
  const float* end_t  = (const float*)d_in[15];
  float* out = (float*)d_out;

  char* ws = (char*)d_ws;
  size_t off = 0;
  auto alloc = [&](size_t bytes) { char* p = ws + off; off += (bytes + 255) & ~(size_t)255; return p; };
  __hip_bfloat16* xbf   = (__hip_bfloat16*)alloc((size_t)NM*NE*2);        // 25.2 MB
  __hip_bfloat16* Wihbf = (__hip_bfloat16*)alloc((size_t)1024*NE*2);      // 1.6 MB
  __hip_bfloat16* whhp  = (__hip_bfloat16*)alloc((size_t)2*512*128*2);    // 0.26 MB
  float*          biasp = (float*)alloc(1024*4);
  __hip_bfloat16* xqd   = (__hip_bfloat16*)alloc((size_t)2*NM*512*2);     // 33.6 MB
  float*          hf    = (float*)alloc((size_t)NM*128*4);                // 8.4 MB
  float*          hb    = (float*)alloc((size_t)NM*128*4);                // 8.4 MB
  float*          em    = (float*)alloc((size_t)NM*15*4);                 // 1.0 MB
  float*          nllb  = (float*)alloc(32*4);
  (void)ws_size; (void)in_sizes; (void)n_in; (void)out_size;

  cvt_bf16_kernel<<<2048, 256, 0, stream>>>(x, xbf, NM*NE/4);
  cvt_wih_perm<<<1024, 256, 0, stream>>>(Wih_f, Wih_b, Wihbf);
  cvt_whh_perm<<<1024, 128, 0, stream>>>(Whh_f, Whh_b, whhp);
  bias_perm_kernel<<<4, 256, 0, stream>>>(bih_f, bhh_f, bih_b, bhh_b, biasp);

  gemm_xproj<<<dim3(128, 8), 256, 0, stream>>>(xbf, Wihbf, biasp, xqd);
  lstm_mfma<<<16, 512, 0, stream>>>(xqd, whhp, hf, hb);
  em_kernel<<<64, 256, 0, stream>>>(hf, hb, Wp, bp, em);
  crf_kernel<<<32, 64, 0, stream>>>(em, tags, mask, trans, start_t, end_t, nllb);
  nll_reduce_kernel<<<1, 64, 0, stream>>>(nllb, out);
}

// Round 14
// 605.397 us; speedup vs baseline: 2.2580x; 1.0086x over previous
//
#include <hip/hip_runtime.h>
#include <hip/hip_bf16.h>
#include <cstdint>

typedef __attribute__((ext_vector_type(8))) short short8;
typedef __attribute__((ext_vector_type(4))) float f32x4;

#define NS 512
#define NB 32
#define NE 768
#define NH 128
#define NT 15
#define NM (NB*NS)      // 16384 rows, m = b*512 + s

#define LOG2E  1.4426950408889634f
#define LOG2E2 2.8853900817779268f

__device__ __forceinline__ float bflo(unsigned int u){ return __builtin_bit_cast(float, u << 16); }
__device__ __forceinline__ float bfhi(unsigned int u){ return __builtin_bit_cast(float, u & 0xffff0000u); }

__device__ __forceinline__ float rcpf_(float x){
#if __has_builtin(__builtin_amdgcn_rcpf)
  return __builtin_amdgcn_rcpf(x);
#else
  return __fdividef(1.f, x);
#endif
}
__device__ __forceinline__ float ex2_(float x){
#if __has_builtin(__builtin_amdgcn_exp2f)
  return __builtin_amdgcn_exp2f(x);
#else
  return exp2f(x);
#endif
}

// raw workgroup barrier: LDS-drain only, global loads/stores stay in flight.
__device__ __forceinline__ void lds_barrier() {
  asm volatile("s_waitcnt lgkmcnt(0)" ::: "memory");
  __builtin_amdgcn_s_barrier();
  asm volatile("" ::: "memory");
}

__device__ __forceinline__ void gload16(const void* g, void* l) {
#if __has_builtin(__builtin_amdgcn_global_load_lds)
  __builtin_amdgcn_global_load_lds((const __attribute__((address_space(1))) void*)g,
                                   (__attribute__((address_space(3))) void*)l, 16, 0, 0);
#else
  *(uint4*)l = *(const uint4*)g;
#endif
}

// ---------------- converts ----------------
__global__ void cvt_bf16_kernel(const float* __restrict__ in,
                                __hip_bfloat16* __restrict__ out, int n4) {
  int i = blockIdx.x*blockDim.x + threadIdx.x;
  int stride = gridDim.x*blockDim.x;
  for (int j = i; j < n4; j += stride) {
    float4 v = ((const float4*)in)[j];
    ushort4 o;
    o.x = __builtin_bit_cast(unsigned short, __float2bfloat16(v.x));
    o.y = __builtin_bit_cast(unsigned short, __float2bfloat16(v.y));
    o.z = __builtin_bit_cast(unsigned short, __float2bfloat16(v.z));
    o.w = __builtin_bit_cast(unsigned short, __float2bfloat16(v.w));
    ((ushort4*)out)[j] = o;
  }
}

// permuted row n = dir*512 + (j*4+g)  <- src row (g*128+j); PRE-SCALED by gate factor
// (log2e for i,f,o; 2*log2e for g) so activations use exp2 directly.
__global__ void cvt_wih_perm(const float* __restrict__ wf, const float* __restrict__ wb,
                             __hip_bfloat16* __restrict__ out) {
  const int n = blockIdx.x;           // 0..1023
  const int dir = n >> 9, cc = n & 511, j = cc >> 2, g = cc & 3;
  const float fac = (g == 2) ? LOG2E2 : LOG2E;
  const float* src = (dir ? wb : wf) + (size_t)(g*128 + j)*768;
  __hip_bfloat16* dst = out + (size_t)n*768;
  for (int e = threadIdx.x; e < 768; e += 256) dst[e] = __float2bfloat16(src[e]*fac);
}

__global__ void cvt_whh_perm(const float* __restrict__ wf, const float* __restrict__ wb,
                             __hip_bfloat16* __restrict__ out) {
  const int n = blockIdx.x;           // 0..1023 = dir*512+cc
  const int dir = n >> 9, cc = n & 511, j = cc >> 2, g = cc & 3;
  const float fac = (g == 2) ? LOG2E2 : LOG2E;
  const float* src = (dir ? wb : wf) + (size_t)(g*128 + j)*128;
  __hip_bfloat16* dst = out + (size_t)n*128;
  if (threadIdx.x < 128) dst[threadIdx.x] = __float2bfloat16(src[threadIdx.x]*fac);
}

__global__ void bias_perm_kernel(const float* __restrict__ bihf, const float* __restrict__ bhhf,
                                 const float* __restrict__ bihb, const float* __restrict__ bhhb,
                                 float* __restrict__ biasp) {
  const int n = blockIdx.x*blockDim.x + threadIdx.x;
  if (n >= 1024) return;
  const int dir = n >> 9, cc = n & 511, g = cc & 3, j = cc >> 2;
  const float fac = (g == 2) ? LOG2E2 : LOG2E;
  const int src = g*128 + j;
  biasp[n] = fac * (dir ? (bihb[src] + bhhb[src]) : (bihf[src] + bhhf[src]));
}

// ---------------- xproj GEMM: A[16384x768] @ Bw[1024x768]^T -> xqd[2][NM][512] ----------------
__global__ __launch_bounds__(256, 2) void gemm_xproj(
    const __hip_bfloat16* __restrict__ A,
    const __hip_bfloat16* __restrict__ Bw,
    const float* __restrict__ biasp,
    __hip_bfloat16* __restrict__ xqd)        // [2][NM][512] packed j*4+g, scaled
{
  __shared__ __align__(16) __hip_bfloat16 As[128*64];
  __shared__ __align__(16) __hip_bfloat16 Bs[128*64];
  const int bm = blockIdx.x * 128;
  const int bn = blockIdx.y * 128;
  const int tid = threadIdx.x;
  const int lane = tid & 63;
  const int wv = tid >> 6;
  const int wr = wv >> 1, wc = wv & 1;
  char* AsB = (char*)As;
  char* BsB = (char*)Bs;
  const char* Ab = (const char*)A;
  const char* Bb = (const char*)Bw;
  f32x4 acc[4][4] = {};

  for (int kt = 0; kt < 12; ++kt) {
    const int k0 = kt * 64;
    __syncthreads();
    #pragma unroll
    for (int i = 0; i < 4; ++i) {
      int fb = i*4096 + tid*16;
      int r  = fb >> 7;
      int cb = fb & 127;
      gload16(Ab + ((size_t)(bm + r)*768 + k0)*2 + cb, AsB + fb);
      gload16(Bb + ((size_t)(bn + r)*768 + k0)*2 + cb, BsB + fb);
    }
    __syncthreads();
    #pragma unroll
    for (int ks = 0; ks < 2; ++ks) {
      const int krow = ks*32 + ((lane >> 4) << 3);
      short8 af[4], bfr[4];
      #pragma unroll
      for (int m = 0; m < 4; ++m) {
        int row = wr*64 + m*16 + (lane & 15);
        af[m] = *(const short8*)(AsB + (row*64 + krow)*2);
      }
      #pragma unroll
      for (int n = 0; n < 4; ++n) {
        int row = wc*64 + n*16 + (lane & 15);
        bfr[n] = *(const short8*)(BsB + (row*64 + krow)*2);
      }
      #pragma unroll
      for (int m = 0; m < 4; ++m)
        #pragma unroll
        for (int n = 0; n < 4; ++n)
          acc[m][n] = __builtin_amdgcn_mfma_f32_16x16x32_bf16(af[m], bfr[n], acc[m][n], 0, 0, 0);
    }
  }
  #pragma unroll
  for (int m = 0; m < 4; ++m) {
    #pragma unroll
    for (int n = 0; n < 4; ++n) {
      const int col = bn + wc*64 + n*16 + (lane & 15);
      const float bv = biasp[col];
      const int dir = col >> 9;
      const int cc  = col & 511;
      #pragma unroll
      for (int jj = 0; jj < 4; ++jj) {
        const int row = bm + wr*64 + m*16 + ((lane >> 4)*4 + jj);
        xqd[((size_t)dir*NM + row)*512 + cc] = __float2bfloat16(acc[m][n][jj] + bv);
      }
    }
  }
}

// ---------------- LSTM: two-phase MFMA, 32 blocks x 256 threads ----------------
// 32 blocks = (dir, bg 0..15), 2 batches each, 4 waves, 1 wave/SIMD.
// Phase A: z[512x16] = Whhp @ h via MFMA (8 rtiles/wave, weights AGPR-pinned).
// Phase B: thread (b2=t&1, j=t>>1) computes one h.
// x: depth-4 rotating registers, pointer-stride addressing, LDS-only barriers.
__global__ __launch_bounds__(256) __attribute__((amdgpu_waves_per_eu(1, 1)))
void lstm_mfma(
    const __hip_bfloat16* __restrict__ xqd,   // [2][NM][512] packed j*4+g, bias folded, scaled
    const __hip_bfloat16* __restrict__ whhp,  // [2][512][128] permuted rows, scaled
    float* __restrict__ hf,                   // [NM][128]
    float* __restrict__ hb)                   // [NM][128]
{
  __shared__ __align__(16) char hfrag[2*4224];   // [buf][kc:1056B][lane:16B] B-frag layout
  __shared__ __align__(16) float z_lds[2*520];   // [b][4*swz(j)] f32x4, swizzled

  const int bid = blockIdx.x;
  const int dir = bid >> 4, bg = bid & 15;
  const int t = threadIdx.x;
  const int w = t >> 6, l = t & 63;
  const int ln = l & 15, lp = l >> 4;

  // A-fragments (weights): wave w rows (w*8+r)*16+ln, k = kc*32 + lp*8 + e.
  uint4 afu[8][4];
  {
    const char* wbase = (const char*)(whhp + (size_t)dir*512*128);
    #pragma unroll
    for (int r = 0; r < 8; ++r) {
      const int row = (w*8 + r)*16 + ln;
      #pragma unroll
      for (int kc = 0; kc < 4; ++kc)
        afu[r][kc] = *(const uint4*)(wbase + ((size_t)row*128 + lp*8 + kc*32)*2);
    }
  }

  for (int i = t; i < 2*4224/4; i += 256) ((int*)hfrag)[i] = 0;

  // phase-B identity
  const int b2 = t & 1, j = t >> 1;
  const int bsafe = bg*2 + b2;
  const int jsw = j ^ ((j >> 3) & 7);
  const int woff = (j >> 5)*1056 + ((j >> 3) & 3)*256 + b2*16 + (j & 7)*2;
  const int sdir = dir ? -1 : 1;
  const int s0 = dir ? 511 : 0;
  const ptrdiff_t xstep = (ptrdiff_t)sdir*512;
  const ptrdiff_t hstep = (ptrdiff_t)sdir*128;
  const __hip_bfloat16* xbase = xqd + ((size_t)dir*NM + (size_t)bsafe*512)*512
                                + (ptrdiff_t)s0*512 + j*4;
  float* hout = (dir ? hb : hf) + (size_t)bsafe*512*128 + (ptrdiff_t)s0*128 + j;

  float c = 0.f;

  // depth-4 rotating x registers
  uint2 x0 = *(const uint2*)(xbase);
  uint2 x1 = *(const uint2*)(xbase + xstep);
  uint2 x2 = *(const uint2*)(xbase + 2*xstep);
  uint2 x3 = *(const uint2*)(xbase + 3*xstep);
  const __hip_bfloat16* xpre = xbase + 4*xstep;   // next address to fetch
  __syncthreads();   // prologue only

  int buf = 0;

  auto STEP = [&](uint2& xc, bool pf) {
    // ---- phase A: B-fragments (lane-linear, conflict-free) + 32 MFMA ----
    short8 bfv[4];
    #pragma unroll
    for (int kc = 0; kc < 4; ++kc)
      bfv[kc] = *(const short8*)(hfrag + buf*4224 + kc*1056 + l*16);

    f32x4 acc[8];
    #pragma unroll
    for (int r = 0; r < 8; ++r) {
      acc[r] = f32x4{0.f, 0.f, 0.f, 0.f};
      #pragma unroll
      for (int kc = 0; kc < 4; ++kc)
        acc[r] = __builtin_amdgcn_mfma_f32_16x16x32_bf16(
                   __builtin_bit_cast(short8, afu[r][kc]), bfv[kc], acc[r], 0, 0, 0);
    }

    // issue x refill into the slot being consumed (stays in flight across barriers)
    uint2 xn;
    if (pf) xn = *(const uint2*)xpre;

    // publish z (real batch cols ln<2 only), XOR-swizzled -> conflict-free
    if (ln < 2) {
      #pragma unroll
      for (int r = 0; r < 8; ++r) {
        const int jw = (w*8 + r)*4 + lp;
        const int js = jw ^ ((jw >> 3) & 7);
        *(f32x4*)&z_lds[ln*520 + 4*js] = acc[r];
      }
    }
    lds_barrier();

    // ---- phase B: one h per thread (exp2 forms, inputs pre-scaled) ----
    const f32x4 zv = *(const f32x4*)&z_lds[b2*520 + 4*jsw];
    const float zi = zv[0] + bflo(xc.x);
    const float zf = zv[1] + bfhi(xc.x);
    const float zg = zv[2] + bflo(xc.y);
    const float zo = zv[3] + bfhi(xc.y);
    const float I = rcpf_(1.f + ex2_(-zi));
    const float F = rcpf_(1.f + ex2_(-zf));
    const float G = 1.f - 2.f*rcpf_(ex2_(zg) + 1.f);
    const float O = rcpf_(1.f + ex2_(-zo));
    c = F*c + I*G;
    const float h = O*(1.f - 2.f*rcpf_(ex2_(c*LOG2E2) + 1.f));

    *(short*)(hfrag + (buf ^ 1)*4224 + woff) =
        (short)__builtin_bit_cast(unsigned short, __float2bfloat16(h));
    *hout = h;                         // fire-and-forget (never drained in-loop)
    hout += hstep;
    if (pf) { xc = xn; xpre += xstep; }
    lds_barrier();
    buf ^= 1;
  };

  for (int it = 0; it < 127; ++it) {   // 508 steps with prefetch
    // AGPR pin (R9-proven residency mechanism)
    #pragma unroll
    for (int r = 0; r < 8; ++r)
      #pragma unroll
      for (int kc = 0; kc < 4; ++kc)
        asm volatile("" : "+a"(afu[r][kc].x), "+a"(afu[r][kc].y),
                          "+a"(afu[r][kc].z), "+a"(afu[r][kc].w));
    STEP(x0, true);
    STEP(x1, true);
    STEP(x2, true);
    STEP(x3, true);
  }
  // epilogue: last 4 steps, no prefetch
  STEP(x0, false);
  STEP(x1, false);
  STEP(x2, false);
  STEP(x3, false);
}

// ---------------- emissions: em[m][t] = [hf|hb][m] . Wp[t] + bp[t] ----------------
__global__ __launch_bounds__(256) void em_kernel(
    const float* __restrict__ hf, const float* __restrict__ hb,
    const float* __restrict__ Wp, const float* __restrict__ bp,
    float* __restrict__ em)
{
  __shared__ float wps[15*256];
  __shared__ float bps[15];
  const int tid = threadIdx.x;
  for (int i = tid; i < 15*256; i += 256) wps[i] = Wp[i];
  if (tid < 15) bps[tid] = bp[tid];
  __syncthreads();
  const size_t m = (size_t)blockIdx.x*256 + tid;
  float acc[15];
  #pragma unroll
  for (int t2 = 0; t2 < 15; ++t2) acc[t2] = bps[t2];
  const float4* hf4 = (const float4*)(hf + m*128);
  const float4* hb4 = (const float4*)(hb + m*128);
  for (int kc = 0; kc < 32; ++kc) {
    float4 hv = hf4[kc];
    #pragma unroll
    for (int t2 = 0; t2 < 15; ++t2)
      acc[t2] += hv.x*wps[t2*256 + kc*4+0] + hv.y*wps[t2*256 + kc*4+1]
               + hv.z*wps[t2*256 + kc*4+2] + hv.w*wps[t2*256 + kc*4+3];
  }
  for (int kc = 0; kc < 32; ++kc) {
    float4 hv = hb4[kc];
    #pragma unroll
    for (int t2 = 0; t2 < 15; ++t2)
      acc[t2] += hv.x*wps[t2*256 + 128 + kc*4+0] + hv.y*wps[t2*256 + 128 + kc*4+1]
               + hv.z*wps[t2*256 + 128 + kc*4+2] + hv.w*wps[t2*256 + 128 + kc*4+3];
  }
  float* eo = em + m*15;
  #pragma unroll
  for (int t2 = 0; t2 < 15; ++t2) eo[t2] = acc[t2];
}

// ---------------- CRF NLL: one block (1 wave) per batch -> partial per b ----------------
__global__ __launch_bounds__(64) void crf_kernel(
    const float* __restrict__ em,
    const int* __restrict__ tags, const int* __restrict__ mask,
    const float* __restrict__ trans, const float* __restrict__ start_t,
    const float* __restrict__ end_t, float* __restrict__ nllb)
{
  __shared__ __align__(16) float ems[512*15];
  __shared__ float trs[225];
  __shared__ int tgs[512];
  __shared__ int mks[512];
  const int b = blockIdx.x, j = threadIdx.x;
  const float* emb = em + (size_t)b*512*15;
  {
    const float4* s4 = (const float4*)emb;
    float4* d4 = (float4*)ems;
    for (int i = j; i < 512*15/4; i += 64) d4[i] = s4[i];
    for (int i = j; i < 512; i += 64) { tgs[i] = tags[b*512+i]; mks[i] = mask[b*512+i]; }
    for (int i = j; i < 225; i += 64) trs[i] = trans[i];
  }
  __syncthreads();

  float trc[15];
  #pragma unroll
  for (int i = 0; i < 15; ++i) trc[i] = (j < 15) ? trs[i*15 + j] : 0.f;

  float alpha = (j < 15) ? (start_t[j] + ems[j]) : -3.0e38f;
  for (int s = 1; s < 512; ++s) {
    const float emv = (j < 15) ? ems[s*15 + j] : 0.f;
    const int msk = mks[s];
    float v[15];
    // alpha_i broadcast via v_readlane (SGPR) instead of 15 ds_bpermute shuffles
    #pragma unroll
    for (int i = 0; i < 15; ++i) {
#if __has_builtin(__builtin_amdgcn_readlane)
      const float ai = __builtin_bit_cast(float,
          __builtin_amdgcn_readlane(__builtin_bit_cast(int, alpha), i));
#else
      const float ai = __shfl(alpha, i, 64);
#endif
      v[i] = ai + trc[i];
    }
    const float t01 = fmaxf(v[0], v[1]),  t23 = fmaxf(v[2], v[3]);
    const float t45 = fmaxf(v[4], v[5]),  t67 = fmaxf(v[6], v[7]);
    const float t89 = fmaxf(v[8], v[9]),  tab = fmaxf(v[10], v[11]);
    const float tcd = fmaxf(v[12], v[13]);
    const float q0 = fmaxf(t01, t23), q1 = fmaxf(t45, t67);
    const float q2 = fmaxf(t89, tab), q3 = fmaxf(tcd, v[14]);
    const float mx = fmaxf(fmaxf(q0, q1), fmaxf(q2, q3));
    float e[15];
    #pragma unroll
    for (int i = 0; i < 15; ++i) e[i] = __expf(v[i] - mx);
    const float s01 = e[0]+e[1], s23 = e[2]+e[3], s45 = e[4]+e[5], s67 = e[6]+e[7];
    const float s89 = e[8]+e[9], sab = e[10]+e[11], scd = e[12]+e[13];
    const float u0 = s01+s23, u1 = s45+s67, u2 = s89+sab, u3 = scd+e[14];
    const float sum = (u0+u1) + (u2+u3);
    const float nxt = emv + mx + __logf(sum);
    if (msk > 0 && j < 15) alpha = nxt;
  }
  float vz = (j < 15) ? (alpha + end_t[j]) : -3.0e38f;
  float mz = vz;
  #pragma unroll
  for (int off = 32; off > 0; off >>= 1) mz = fmaxf(mz, __shfl_xor(mz, off, 64));
  float se = (j < 15) ? __expf(vz - mz) : 0.f;
  #pragma unroll
  for (int off = 32; off > 0; off >>= 1) se += __shfl_xor(se, off, 64);
  const float logZ = mz + __logf(se);

  float sc = 0.f; int cnt = 0;
  for (int s = j; s < 512; s += 64) cnt += (mks[s] ? 1 : 0);
  for (int s = 1 + j; s < 512; s += 64) {
    if (mks[s]) {
      const int tp = tgs[s-1], tc = tgs[s];
      sc += trs[tp*15 + tc] + ems[s*15 + tc];
    }
  }
  #pragma unroll
  for (int off = 32; off > 0; off >>= 1) {
    sc  += __shfl_xor(sc, off, 64);
    cnt += __shfl_xor(cnt, off, 64);
  }
  if (j == 0) {
    const int t0 = tgs[0];
    sc += start_t[t0] + ems[t0];
    int last = cnt - 1; if (last < 0) last = 0;
    sc += end_t[tgs[last]];
    nllb[b] = logZ - sc;
  }
}

__global__ __launch_bounds__(64) void nll_reduce_kernel(const float* __restrict__ nllb,
                                                        float* __restrict__ out) {
  const int j = threadIdx.x;
  float v = (j < 32) ? nllb[j] : 0.f;
  #pragma unroll
  for (int off = 32; off > 0; off >>= 1) v += __shfl_xor(v, off, 64);
  if (j == 0) out[0] = v;
}

// ---------------- launch ----------------
extern "C" void kernel_launch(void* const* d_in, const int* in_sizes, int n_in,
                              void* d_out, int out_size, void* d_ws, size_t ws_size,
                              hipStream_t stream) {
  const float* x      = (const float*)d_in[0];
  const int*   tags   = (const int*)d_in[1];
  const int*   mask   = (const int*)d_in[2];
  const float* Wih_f  = (const float*)d_in[3];
  const float* Whh_f  = (const float*)d_in[4];
  const float* bih_f  = (const float*)d_in[5];
  const float* bhh_f  = (const float*)d_in[6];
  const float* Wih_b  = (const float*)d_in[7];
  const float* Whh_b  = (const float*)d_in[8];
  const float* bih_b  = (const float*)d_in[9];
  const float* bhh_b  = (const float*)d_in[10];
  const float* Wp     = (const float*)d_in[11];
  const float* bp     = (const float*)d_in[12];
  const float* trans  = (const float*)d_in[13];
  const float* start_t= (const float*)d_in[14];
  const float* end_t  = (const float*)d_in[15];
  float* out = (float*)d_out;

  char* ws = (char*)d_ws;
  size_t off = 0;
  auto alloc = [&](size_t bytes) { char* p = ws + off; off += (bytes + 255) & ~(size_t)255; return p; };
  __hip_bfloat16* xbf   = (__hip_bfloat16*)alloc((size_t)NM*NE*2);        // 25.2 MB
  __hip_bfloat16* Wihbf = (__hip_bfloat16*)alloc((size_t)1024*NE*2);      // 1.6 MB
  __hip_bfloat16* whhp  = (__hip_bfloat16*)alloc((size_t)2*512*128*2);    // 0.26 MB
  float*          biasp = (float*)alloc(1024*4);
  __hip_bfloat16* xqd   = (__hip_bfloat16*)alloc((size_t)2*NM*512*2);     // 33.6 MB
  float*          hf    = (float*)alloc((size_t)NM*128*4);                // 8.4 MB
  float*          hb    = (float*)alloc((size_t)NM*128*4);                // 8.4 MB
  float*          em    = (float*)alloc((size_t)NM*15*4);                 // 1.0 MB
  float*          nllb  = (float*)alloc(32*4);
  (void)ws_size; (void)in_sizes; (void)n_in; (void)out_size;

  cvt_bf16_kernel<<<2048, 256, 0, stream>>>(x, xbf, NM*NE/4);
  cvt_wih_perm<<<1024, 256, 0, stream>>>(Wih_f, Wih_b, Wihbf);
  cvt_whh_perm<<<1024, 128, 0, stream>>>(Whh_f, Whh_b, whhp);
  bias_perm_kernel<<<4, 256, 0, stream>>>(bih_f, bhh_f, bih_b, bhh_b, biasp);

  gemm_xproj<<<dim3(128, 8), 256, 0, stream>>>(xbf, Wihbf, biasp, xqd);
  lstm_mfma<<<32, 256, 0, stream>>>(xqd, whhp, hf, hb);
  em_kernel<<<64, 256, 0, stream>>>(hf, hb, Wp, bp, em);
  crf_kernel<<<32, 64, 0, stream>>>(em, tags, mask, trans, start_t, end_t, nllb);
  nll_reduce_kernel<<<1, 64, 0, stream>>>(nllb, out);
}